// Round 5
// baseline (479.239 us; speedup 1.0000x reference)
//
#include <hip/hip_runtime.h>
#include <math.h>

typedef _Float16 Hh;
typedef __attribute__((ext_vector_type(8))) _Float16 half8;
typedef __attribute__((ext_vector_type(4))) _Float16 half4;
typedef __attribute__((ext_vector_type(4))) float float4v;

#define B_ 2
#define H_ 16
#define N_ 2048
#define D_ 64
#define ND_ (N_*D_)
#define C1 0.04508422f   // (1/32)*log2(e); softmax in base-2 throughout

// Barrier WITHOUT the vmcnt(0) drain __syncthreads would emit.
#define BAR() asm volatile("s_waitcnt lgkmcnt(0)\n\ts_barrier" ::: "memory")

// attend LDS layouts (i-tile 32), conflict-free strides (R2-proven):
// Ebuf: [j(32)][i(32)][f(16+4pad)]  j-stride 644 halves, i-stride 20
#define EB_JS 644
#define EB_IS 20
// Pm: [e(16)][i(32)][j(32+4pad)]    e-stride 1156 halves, i-stride 36
#define PM_ES 1156
#define PM_IS 36

// ---------------------------------------------------------------------------
// K1: prep. (unchanged)
// ---------------------------------------------------------------------------
__global__ __launch_bounds__(256,2) void prep_kernel(const float* __restrict__ q,
    const float* __restrict__ k, const float* __restrict__ v,
    const float* __restrict__ Wpre,
    Hh* __restrict__ qb, Hh* __restrict__ kb, Hh* __restrict__ vt2,
    float4* __restrict__ out4, float4* __restrict__ lacc4)
{
    int tid = threadIdx.x;
    int bid = blockIdx.x;
    if (bid < 512) {
        __shared__ float wsh[256];
        wsh[tid] = Wpre[tid];
        __syncthreads();
        int tensor = bid >> 8;
        int g = ((bid & 255) << 8) | tid;     // 0 .. 65535
        int b = g >> 15;
        int r = g & 32767;                    // (n,d4): n*16 + d4
        const float4* src = (const float4*)(tensor ? k : q);
        Hh* dst = tensor ? kb : qb;
        float4 x[16];
        #pragma unroll
        for (int f=0; f<16; f++) x[f] = src[(size_t)(b*16+f)*32768 + r];
        #pragma unroll
        for (int e=0; e<16; e++) {
            float4 a = make_float4(0.f,0.f,0.f,0.f);
            #pragma unroll
            for (int f=0; f<16; f++) {
                float wv = wsh[e*16+f];
                a.x += wv*x[f].x; a.y += wv*x[f].y; a.z += wv*x[f].z; a.w += wv*x[f].w;
            }
            half4 hv; hv[0]=(Hh)a.x; hv[1]=(Hh)a.y; hv[2]=(Hh)a.z; hv[3]=(Hh)a.w;
            *(half4*)(dst + (size_t)(b*16+e)*ND_ + (size_t)r*4) = hv;
        }
    } else if (bid < 768) {
        __shared__ Hh tile[64*48];            // [d][j], stride 48 halves
        int tb = bid - 512;                   // 0..255
        int be = tb >> 3;                     // 0..31
        int jtg = tb & 7;
        const float4* v4 = (const float4*)v;
        for (int u=0; u<8; u++) {
            int jt = jtg*8 + u;               // 0..63
            #pragma unroll
            for (int p=0; p<2; p++) {
                int j = p*16 + (tid>>4);
                int d4 = tid & 15;
                float4 val = v4[(size_t)be*32768 + (size_t)(jt*32+j)*16 + d4];
                tile[(d4*4+0)*48 + j] = (Hh)val.x;
                tile[(d4*4+1)*48 + j] = (Hh)val.y;
                tile[(d4*4+2)*48 + j] = (Hh)val.z;
                tile[(d4*4+3)*48 + j] = (Hh)val.w;
            }
            BAR();
            {
                int d = tid >> 2;
                int jc = (tid & 3) * 8;
                half8 o;
                #pragma unroll
                for (int z=0; z<8; z++) o[z] = tile[d*48 + jc + z];
                *(half8*)(vt2 + ((size_t)(be*64) + jt)*2048 + (size_t)tid*8) = o;
            }
            BAR();
        }
    } else {
        // zero out + lacc. out = 2*16*2048*64 floats = 1048576 float4.
        int zid = (bid - 768) * 256 + tid;    // 0 .. 262143
        float4 zz = make_float4(0.f,0.f,0.f,0.f);
        #pragma unroll
        for (int u=0; u<4; u++) out4[(size_t)u*262144 + zid] = zz;
        if (zid < 16384) lacc4[zid] = zz;
    }
}

// ---------------------------------------------------------------------------
// K2: denominators (R4 version: register-lean + K prefetch, no spills).
// ---------------------------------------------------------------------------
__global__ __launch_bounds__(1024,4) void denom_kernel(const Hh* __restrict__ qb,
    const Hh* __restrict__ kb, float* __restrict__ lacc_g)
{
    int bid = blockIdx.x;                 // 0..511
    int s = bid & 7;                      // j-slab, XCD-aligned
    int idx = bid >> 3;                   // 0..63
    int b = idx & 1;
    int pr = idx >> 1;                    // 0..31: triangle pair id
    int tid = threadIdx.x;
    int lane = tid & 63, w = tid >> 6;    // w = head f, 0..15
    int qd = lane >> 4, c = lane & 15;

    const Hh* qh = qb + (size_t)(b*16 + w)*ND_;
    const Hh* kh = kb + (size_t)(b*16 + w)*ND_;

    for (int hf = 0; hf < 2; hf++) {
        int it = hf ? (63 - pr) : pr;     // 32-row i-tile index
        if (s > it) continue;
        int i0 = it * 32;

        half8 aq[2][2];
        #pragma unroll
        for (int ig=0; ig<2; ig++) {
            const Hh* qr = qh + (size_t)(i0 + ig*16 + c)*64 + qd*8;
            aq[ig][0] = *(const half8*)qr;
            aq[ig][1] = *(const half8*)(qr+32);
        }
        float lacc[2][4];
        #pragma unroll
        for (int ig=0; ig<2; ig++)
            #pragma unroll
            for (int r=0; r<4; r++) lacc[ig][r] = 0.f;

        auto loadK = [&](int jt, half8 (&kk)[2][2]) {
            #pragma unroll
            for (int jh=0; jh<2; jh++) {
                const Hh* kr = kh + (size_t)(jt*32 + jh*16 + c)*64 + qd*8;
                kk[jh][0] = *(const half8*)kr;
                kk[jh][1] = *(const half8*)(kr+32);
            }
        };

        half8 ka[2][2];
        loadK(s, ka);
        for (int jt = s; jt <= it; jt += 8) {
            bool more = (jt + 8 <= it);
            half8 kn[2][2];
            if (more) loadK(jt + 8, kn);
            #pragma unroll
            for (int jh=0; jh<2; jh++) {
                int j = jt*32 + jh*16 + c;
                #pragma unroll
                for (int ig=0; ig<2; ig++) {
                    float4v sv = {0.f,0.f,0.f,0.f};
                    sv = __builtin_amdgcn_mfma_f32_16x16x32_f16(aq[ig][0], ka[jh][0], sv, 0,0,0);
                    sv = __builtin_amdgcn_mfma_f32_16x16x32_f16(aq[ig][1], ka[jh][1], sv, 0,0,0);
                    #pragma unroll
                    for (int r=0; r<4; r++) {
                        int i = i0 + ig*16 + qd*4 + r;
                        float ev = (j <= i) ? __builtin_amdgcn_exp2f(sv[r]*C1) : 0.f;
                        lacc[ig][r] += ev;
                    }
                }
            }
            if (more) {
                #pragma unroll
                for (int jh=0; jh<2; jh++) {
                    ka[jh][0] = kn[jh][0];
                    ka[jh][1] = kn[jh][1];
                }
            }
        }
        #pragma unroll
        for (int ig=0; ig<2; ig++) {
            #pragma unroll
            for (int r=0; r<4; r++) {
                float vs = lacc[ig][r];
                vs += __shfl_xor(vs, 1);
                vs += __shfl_xor(vs, 2);
                vs += __shfl_xor(vs, 4);
                vs += __shfl_xor(vs, 8);
                if (c == 0)
                    unsafeAtomicAdd(&lacc_g[(size_t)(b*16+w)*N_ + i0 + ig*16 + qd*4 + r], vs);
            }
        }
    }
}

// ---------------------------------------------------------------------------
// K3: main fused pass — R3 base (fastest measured: register-lean,
// 1 head/wave in every role, VGPR 64) with TWO changes:
//  (1) 8 j-slabs instead of 4 -> 512 blocks, ~10 j-iters/block (half the
//      serial latency chain) and 2 blocks/CU co-resident (78.2 KB LDS x2 =
//      156.7 KB <= 160 KB) so one block's compute hides the other's load/
//      barrier stalls.
//  (2) Pm stride 1280 -> 1156 halves (2560 B was = 0 mod 128 B: 16-way bank
//      conflict on every Pm access; 1156 is the R2-proven clean stride).
// ---------------------------------------------------------------------------
__global__ __launch_bounds__(1024,8) void attend_kernel(const Hh* __restrict__ qb,
    const Hh* __restrict__ kb, const Hh* __restrict__ vt2,
    const float* __restrict__ lacc_g, const float* __restrict__ Wpost,
    float* __restrict__ out)
{
    __shared__ Hh Ebuf[32*EB_JS];   // 41216 B
    __shared__ Hh Pm[16*PM_ES];     // 36992 B

    int bid = blockIdx.x;                      // 0..511
    int s = bid & 7;                           // slab 0..7, XCD-aligned
    int idx = bid >> 3;                        // 0..63
    int b = idx & 1;
    int pr = idx >> 1;                         // 0..31: triangle pair id

    int tid = threadIdx.x;
    int lane = tid & 63, w = tid >> 6;         // w 0..15
    int qd = lane >> 4, c = lane & 15;

    // ---- mix role constants
    int jh2 = w & 1, ib = 4*(w >> 1);
    half4 wf;   // B[k=f=qd*4+z][n=e=c] = Wpost[e][f]
    #pragma unroll
    for (int z=0; z<4; z++) wf[z] = (Hh)Wpost[c*16 + qd*4 + z];

    for (int hf = 0; hf < 2; hf++) {
        int it = hf ? (63 - pr) : pr;          // 32-row i-tile index
        if (s > it) continue;                  // uniform per block
        int i0 = it * 32;

        // ---- scores state: head f = w, both ig
        half8 aq[2][2];
        float lgr[2][4];
        #pragma unroll
        for (int ig=0; ig<2; ig++) {
            const Hh* qr = qb + (size_t)((b*16+w)*N_ + i0 + ig*16 + c)*64 + qd*8;
            aq[ig][0] = *(const half8*)qr;
            aq[ig][1] = *(const half8*)(qr+32);
            #pragma unroll
            for (int r=0; r<4; r++)
                lgr[ig][r] = __builtin_amdgcn_logf(
                    lacc_g[(size_t)(b*16+w)*N_ + i0 + ig*16 + qd*4 + r]);
        }

        float4v acc[2][4];
        #pragma unroll
        for (int ig=0; ig<2; ig++) for (int nc=0; nc<4; nc++)
            acc[ig][nc] = (float4v){0.f,0.f,0.f,0.f};

        auto scores = [&](int jt) {
            #pragma unroll
            for (int jh=0; jh<2; jh++) {
                int jc = jt*32 + jh*16;
                const Hh* kr = kb + (size_t)((b*16+w)*N_ + jc + c)*64 + qd*8;
                half8 b0 = *(const half8*)kr;
                half8 b1 = *(const half8*)(kr+32);
                int j = jc + c;
                #pragma unroll
                for (int ig=0; ig<2; ig++) {
                    float4v sv = {0.f,0.f,0.f,0.f};
                    sv = __builtin_amdgcn_mfma_f32_16x16x32_f16(aq[ig][0], b0, sv, 0,0,0);
                    sv = __builtin_amdgcn_mfma_f32_16x16x32_f16(aq[ig][1], b1, sv, 0,0,0);
                    #pragma unroll
                    for (int r=0; r<4; r++) {
                        int i = i0 + ig*16 + qd*4 + r;
                        float ev = (j <= i) ?
                            __builtin_amdgcn_exp2f(sv[r]*C1 - lgr[ig][r]) : 0.f;
                        Ebuf[(size_t)(jh*16+c)*EB_JS + (ig*16+qd*4+r)*EB_IS + w] = (Hh)ev;
                    }
                }
            }
        };

        scores(s);
        BAR();

        for (int jt = s; jt <= it; jt += 8) {
            // ---- head mix: Pm[e,i,j] for this wave's (jh2, i-quad) ----
            #pragma unroll
            for (int ii=0; ii<4; ii++) {
                int i = ib + ii;
                half4 ef = *(const half4*)&Ebuf[(jh2*16+c)*EB_JS + i*EB_IS + qd*4];
                float4v cc = {0.f,0.f,0.f,0.f};
                cc = __builtin_amdgcn_mfma_f32_16x16x16f16(ef, wf, cc, 0,0,0);
                half4 hv;
                #pragma unroll
                for (int r=0; r<4; r++) hv[r] = (Hh)cc[r];
                *(half4*)&Pm[c*PM_ES + i*PM_IS + jh2*16 + qd*4] = hv;
            }
            BAR();
            // ---- PV(jt): head e=w, both ig; overlap scores(jt+8) ----
            #pragma unroll
            for (int nc=0; nc<4; nc++) {
                const Hh* vr = vt2 + (size_t)((b*16+w)*64 + jt)*2048 + (nc*16+c)*32 + qd*8;
                half8 vb = *(const half8*)vr;
                #pragma unroll
                for (int ig=0; ig<2; ig++) {
                    half8 pa = *(const half8*)&Pm[w*PM_ES + (ig*16+c)*PM_IS + qd*8];
                    acc[ig][nc] = __builtin_amdgcn_mfma_f32_16x16x32_f16(pa, vb, acc[ig][nc], 0,0,0);
                }
            }
            if (jt + 8 <= it) scores(jt + 8);
            BAR();
        }

        // ---- accumulate partial O (nc order rotated by slab) ----
        #pragma unroll
        for (int ig=0; ig<2; ig++) {
            #pragma unroll
            for (int nc0=0; nc0<4; nc0++) {
                int nc = (nc0 + s) & 3;
                #pragma unroll
                for (int r=0; r<4; r++)
                    unsafeAtomicAdd(&out[(size_t)((b*16+w)*N_ + i0 + ig*16 + qd*4 + r)*64 + nc*16 + c],
                                    acc[ig][nc][r]);
            }
        }
    }
}

extern "C" void kernel_launch(void* const* d_in, const int* in_sizes, int n_in,
                              void* d_out, int out_size, void* d_ws, size_t ws_size,
                              hipStream_t stream) {
    const float* q     = (const float*)d_in[0];
    const float* k     = (const float*)d_in[1];
    const float* v     = (const float*)d_in[2];
    const float* Wpre  = (const float*)d_in[3];
    const float* Wpost = (const float*)d_in[4];
    float* out = (float*)d_out;

    size_t tsz = (size_t)B_*H_*N_*D_;       // 4 Mi halves = 8 MB each
    Hh* qb = (Hh*)d_ws;
    Hh* kb = qb + tsz;
    Hh* vt2 = kb + tsz;
    float* lacc = (float*)(vt2 + tsz);      // 24 MB offset, 256 KB

    prep_kernel<<<1792, 256, 0, stream>>>(q, k, v, Wpre, qb, kb, vt2,
                                          (float4*)out, (float4*)lacc);
    denom_kernel<<<512, 1024, 0, stream>>>(qb, kb, lacc);
    attend_kernel<<<512, 1024, 0, stream>>>(qb, kb, vt2, lacc, Wpost, out);
}

// Round 6
// 269.398 us; speedup vs baseline: 1.7789x; 1.7789x over previous
//
#include <hip/hip_runtime.h>
#include <math.h>

typedef _Float16 Hh;
typedef __attribute__((ext_vector_type(8))) _Float16 half8;
typedef __attribute__((ext_vector_type(4))) _Float16 half4;
typedef __attribute__((ext_vector_type(4))) float float4v;

#define B_ 2
#define H_ 16
#define N_ 2048
#define D_ 64
#define ND_ (N_*D_)
#define C1 0.04508422f   // (1/32)*log2(e); softmax in base-2 throughout

// Barrier WITHOUT the vmcnt(0) drain __syncthreads would emit.
#define BAR() asm volatile("s_waitcnt lgkmcnt(0)\n\ts_barrier" ::: "memory")

// attend LDS layouts (i-tile 32), conflict-free strides (R2-proven):
// Ebuf: [j(32)][i(32)][f(16+4pad)]  j-stride 644 halves, i-stride 20
#define EB_JS 644
#define EB_IS 20
// Pm: [e(16)][i(32)][j(32+4pad)]    e-stride 1156 halves, i-stride 36
#define PM_ES 1156
#define PM_IS 36

// ---------------------------------------------------------------------------
// K1: prep. NO launch_bounds: the (256,2) variant cost ~13 µs of "rest"
// (R1/R2 rest ~125 vs R3/R4 ~139-141). Let the allocator do its thing.
// ---------------------------------------------------------------------------
__global__ void prep_kernel(const float* __restrict__ q,
    const float* __restrict__ k, const float* __restrict__ v,
    const float* __restrict__ Wpre,
    Hh* __restrict__ qb, Hh* __restrict__ kb, Hh* __restrict__ vt2,
    float4* __restrict__ out4, float4* __restrict__ lacc4)
{
    int tid = threadIdx.x;
    int bid = blockIdx.x;
    if (bid < 512) {
        __shared__ float wsh[256];
        wsh[tid] = Wpre[tid];
        __syncthreads();
        int tensor = bid >> 8;
        int g = ((bid & 255) << 8) | tid;     // 0 .. 65535
        int b = g >> 15;
        int r = g & 32767;                    // (n,d4): n*16 + d4
        const float4* src = (const float4*)(tensor ? k : q);
        Hh* dst = tensor ? kb : qb;
        float4 x[16];
        #pragma unroll
        for (int f=0; f<16; f++) x[f] = src[(size_t)(b*16+f)*32768 + r];
        #pragma unroll
        for (int e=0; e<16; e++) {
            float4 a = make_float4(0.f,0.f,0.f,0.f);
            #pragma unroll
            for (int f=0; f<16; f++) {
                float wv = wsh[e*16+f];
                a.x += wv*x[f].x; a.y += wv*x[f].y; a.z += wv*x[f].z; a.w += wv*x[f].w;
            }
            half4 hv; hv[0]=(Hh)a.x; hv[1]=(Hh)a.y; hv[2]=(Hh)a.z; hv[3]=(Hh)a.w;
            *(half4*)(dst + (size_t)(b*16+e)*ND_ + (size_t)r*4) = hv;
        }
    } else if (bid < 768) {
        __shared__ Hh tile[64*48];            // [d][j], stride 48 halves
        int tb = bid - 512;                   // 0..255
        int be = tb >> 3;                     // 0..31
        int jtg = tb & 7;
        const float4* v4 = (const float4*)v;
        for (int u=0; u<8; u++) {
            int jt = jtg*8 + u;               // 0..63
            #pragma unroll
            for (int p=0; p<2; p++) {
                int j = p*16 + (tid>>4);
                int d4 = tid & 15;
                float4 val = v4[(size_t)be*32768 + (size_t)(jt*32+j)*16 + d4];
                tile[(d4*4+0)*48 + j] = (Hh)val.x;
                tile[(d4*4+1)*48 + j] = (Hh)val.y;
                tile[(d4*4+2)*48 + j] = (Hh)val.z;
                tile[(d4*4+3)*48 + j] = (Hh)val.w;
            }
            BAR();
            {
                int d = tid >> 2;
                int jc = (tid & 3) * 8;
                half8 o;
                #pragma unroll
                for (int z=0; z<8; z++) o[z] = tile[d*48 + jc + z];
                *(half8*)(vt2 + ((size_t)(be*64) + jt)*2048 + (size_t)tid*8) = o;
            }
            BAR();
        }
    } else {
        // zero out + lacc. out = 2*16*2048*64 floats = 1048576 float4.
        int zid = (bid - 768) * 256 + tid;    // 0 .. 262143
        float4 zz = make_float4(0.f,0.f,0.f,0.f);
        #pragma unroll
        for (int u=0; u<4; u++) out4[(size_t)u*262144 + zid] = zz;
        if (zid < 16384) lacc4[zid] = zz;
    }
}

// ---------------------------------------------------------------------------
// K2: denominators (unchanged: register-lean + K prefetch, no spills).
// ---------------------------------------------------------------------------
__global__ __launch_bounds__(1024,4) void denom_kernel(const Hh* __restrict__ qb,
    const Hh* __restrict__ kb, float* __restrict__ lacc_g)
{
    int bid = blockIdx.x;                 // 0..511
    int s = bid & 7;                      // j-slab, XCD-aligned
    int idx = bid >> 3;                   // 0..63
    int b = idx & 1;
    int pr = idx >> 1;                    // 0..31: triangle pair id
    int tid = threadIdx.x;
    int lane = tid & 63, w = tid >> 6;    // w = head f, 0..15
    int qd = lane >> 4, c = lane & 15;

    const Hh* qh = qb + (size_t)(b*16 + w)*ND_;
    const Hh* kh = kb + (size_t)(b*16 + w)*ND_;

    for (int hf = 0; hf < 2; hf++) {
        int it = hf ? (63 - pr) : pr;     // 32-row i-tile index
        if (s > it) continue;
        int i0 = it * 32;

        half8 aq[2][2];
        #pragma unroll
        for (int ig=0; ig<2; ig++) {
            const Hh* qr = qh + (size_t)(i0 + ig*16 + c)*64 + qd*8;
            aq[ig][0] = *(const half8*)qr;
            aq[ig][1] = *(const half8*)(qr+32);
        }
        float lacc[2][4];
        #pragma unroll
        for (int ig=0; ig<2; ig++)
            #pragma unroll
            for (int r=0; r<4; r++) lacc[ig][r] = 0.f;

        auto loadK = [&](int jt, half8 (&kk)[2][2]) {
            #pragma unroll
            for (int jh=0; jh<2; jh++) {
                const Hh* kr = kh + (size_t)(jt*32 + jh*16 + c)*64 + qd*8;
                kk[jh][0] = *(const half8*)kr;
                kk[jh][1] = *(const half8*)(kr+32);
            }
        };

        half8 ka[2][2];
        loadK(s, ka);
        for (int jt = s; jt <= it; jt += 8) {
            bool more = (jt + 8 <= it);
            half8 kn[2][2];
            if (more) loadK(jt + 8, kn);
            #pragma unroll
            for (int jh=0; jh<2; jh++) {
                int j = jt*32 + jh*16 + c;
                #pragma unroll
                for (int ig=0; ig<2; ig++) {
                    float4v sv = {0.f,0.f,0.f,0.f};
                    sv = __builtin_amdgcn_mfma_f32_16x16x32_f16(aq[ig][0], ka[jh][0], sv, 0,0,0);
                    sv = __builtin_amdgcn_mfma_f32_16x16x32_f16(aq[ig][1], ka[jh][1], sv, 0,0,0);
                    #pragma unroll
                    for (int r=0; r<4; r++) {
                        int i = i0 + ig*16 + qd*4 + r;
                        float ev = (j <= i) ? __builtin_amdgcn_exp2f(sv[r]*C1) : 0.f;
                        lacc[ig][r] += ev;
                    }
                }
            }
            if (more) {
                #pragma unroll
                for (int jh=0; jh<2; jh++) {
                    ka[jh][0] = kn[jh][0];
                    ka[jh][1] = kn[jh][1];
                }
            }
        }
        #pragma unroll
        for (int ig=0; ig<2; ig++) {
            #pragma unroll
            for (int r=0; r<4; r++) {
                float vs = lacc[ig][r];
                vs += __shfl_xor(vs, 1);
                vs += __shfl_xor(vs, 2);
                vs += __shfl_xor(vs, 4);
                vs += __shfl_xor(vs, 8);
                if (c == 0)
                    unsafeAtomicAdd(&lacc_g[(size_t)(b*16+w)*N_ + i0 + ig*16 + qd*4 + r], vs);
            }
        }
    }
}

// ---------------------------------------------------------------------------
// K3: main fused pass — R5's structure (8 slabs -> 512 blocks, Pm 1156)
// with launch_bounds(1024,4) [NOT 8]: R3's code body compiled to 64 VGPR at
// this bound, so 2 blocks/CU co-residency (8 waves/SIMD x 64 VGPR = 512,
// 2 x 78.2 KB LDS <= 160 KB) happens NATURALLY — R5's (1024,8) instead
// forced a 32-VGPR allocation and spilled everything (FETCH 508 MB).
// ---------------------------------------------------------------------------
__global__ __launch_bounds__(1024,4) void attend_kernel(const Hh* __restrict__ qb,
    const Hh* __restrict__ kb, const Hh* __restrict__ vt2,
    const float* __restrict__ lacc_g, const float* __restrict__ Wpost,
    float* __restrict__ out)
{
    __shared__ Hh Ebuf[32*EB_JS];   // 41216 B
    __shared__ Hh Pm[16*PM_ES];     // 36992 B

    int bid = blockIdx.x;                      // 0..511
    int s = bid & 7;                           // slab 0..7, XCD-aligned
    int idx = bid >> 3;                        // 0..63
    int b = idx & 1;
    int pr = idx >> 1;                         // 0..31: triangle pair id

    int tid = threadIdx.x;
    int lane = tid & 63, w = tid >> 6;         // w 0..15
    int qd = lane >> 4, c = lane & 15;

    // ---- mix role constants
    int jh2 = w & 1, ib = 4*(w >> 1);
    half4 wf;   // B[k=f=qd*4+z][n=e=c] = Wpost[e][f]
    #pragma unroll
    for (int z=0; z<4; z++) wf[z] = (Hh)Wpost[c*16 + qd*4 + z];

    for (int hf = 0; hf < 2; hf++) {
        int it = hf ? (63 - pr) : pr;          // 32-row i-tile index
        if (s > it) continue;                  // uniform per block
        int i0 = it * 32;

        // ---- scores state: head f = w, both ig
        half8 aq[2][2];
        float lgr[2][4];
        #pragma unroll
        for (int ig=0; ig<2; ig++) {
            const Hh* qr = qb + (size_t)((b*16+w)*N_ + i0 + ig*16 + c)*64 + qd*8;
            aq[ig][0] = *(const half8*)qr;
            aq[ig][1] = *(const half8*)(qr+32);
            #pragma unroll
            for (int r=0; r<4; r++)
                lgr[ig][r] = __builtin_amdgcn_logf(
                    lacc_g[(size_t)(b*16+w)*N_ + i0 + ig*16 + qd*4 + r]);
        }

        float4v acc[2][4];
        #pragma unroll
        for (int ig=0; ig<2; ig++) for (int nc=0; nc<4; nc++)
            acc[ig][nc] = (float4v){0.f,0.f,0.f,0.f};

        auto scores = [&](int jt) {
            #pragma unroll
            for (int jh=0; jh<2; jh++) {
                int jc = jt*32 + jh*16;
                const Hh* kr = kb + (size_t)((b*16+w)*N_ + jc + c)*64 + qd*8;
                half8 b0 = *(const half8*)kr;
                half8 b1 = *(const half8*)(kr+32);
                int j = jc + c;
                #pragma unroll
                for (int ig=0; ig<2; ig++) {
                    float4v sv = {0.f,0.f,0.f,0.f};
                    sv = __builtin_amdgcn_mfma_f32_16x16x32_f16(aq[ig][0], b0, sv, 0,0,0);
                    sv = __builtin_amdgcn_mfma_f32_16x16x32_f16(aq[ig][1], b1, sv, 0,0,0);
                    #pragma unroll
                    for (int r=0; r<4; r++) {
                        int i = i0 + ig*16 + qd*4 + r;
                        float ev = (j <= i) ?
                            __builtin_amdgcn_exp2f(sv[r]*C1 - lgr[ig][r]) : 0.f;
                        Ebuf[(size_t)(jh*16+c)*EB_JS + (ig*16+qd*4+r)*EB_IS + w] = (Hh)ev;
                    }
                }
            }
        };

        scores(s);
        BAR();

        for (int jt = s; jt <= it; jt += 8) {
            // ---- head mix: Pm[e,i,j] for this wave's (jh2, i-quad) ----
            #pragma unroll
            for (int ii=0; ii<4; ii++) {
                int i = ib + ii;
                half4 ef = *(const half4*)&Ebuf[(jh2*16+c)*EB_JS + i*EB_IS + qd*4];
                float4v cc = {0.f,0.f,0.f,0.f};
                cc = __builtin_amdgcn_mfma_f32_16x16x16f16(ef, wf, cc, 0,0,0);
                half4 hv;
                #pragma unroll
                for (int r=0; r<4; r++) hv[r] = (Hh)cc[r];
                *(half4*)&Pm[c*PM_ES + i*PM_IS + jh2*16 + qd*4] = hv;
            }
            BAR();
            // ---- PV(jt): head e=w, both ig; overlap scores(jt+8) ----
            #pragma unroll
            for (int nc=0; nc<4; nc++) {
                const Hh* vr = vt2 + (size_t)((b*16+w)*64 + jt)*2048 + (nc*16+c)*32 + qd*8;
                half8 vb = *(const half8*)vr;
                #pragma unroll
                for (int ig=0; ig<2; ig++) {
                    half8 pa = *(const half8*)&Pm[w*PM_ES + (ig*16+c)*PM_IS + qd*8];
                    acc[ig][nc] = __builtin_amdgcn_mfma_f32_16x16x32_f16(pa, vb, acc[ig][nc], 0,0,0);
                }
            }
            if (jt + 8 <= it) scores(jt + 8);
            BAR();
        }

        // ---- accumulate partial O (nc order rotated by slab) ----
        #pragma unroll
        for (int ig=0; ig<2; ig++) {
            #pragma unroll
            for (int nc0=0; nc0<4; nc0++) {
                int nc = (nc0 + s) & 3;
                #pragma unroll
                for (int r=0; r<4; r++)
                    unsafeAtomicAdd(&out[(size_t)((b*16+w)*N_ + i0 + ig*16 + qd*4 + r)*64 + nc*16 + c],
                                    acc[ig][nc][r]);
            }
        }
    }
}

extern "C" void kernel_launch(void* const* d_in, const int* in_sizes, int n_in,
                              void* d_out, int out_size, void* d_ws, size_t ws_size,
                              hipStream_t stream) {
    const float* q     = (const float*)d_in[0];
    const float* k     = (const float*)d_in[1];
    const float* v     = (const float*)d_in[2];
    const float* Wpre  = (const float*)d_in[3];
    const float* Wpost = (const float*)d_in[4];
    float* out = (float*)d_out;

    size_t tsz = (size_t)B_*H_*N_*D_;       // 4 Mi halves = 8 MB each
    Hh* qb = (Hh*)d_ws;
    Hh* kb = qb + tsz;
    Hh* vt2 = kb + tsz;
    float* lacc = (float*)(vt2 + tsz);      // 24 MB offset, 256 KB

    prep_kernel<<<1792, 256, 0, stream>>>(q, k, v, Wpre, qb, kb, vt2,
                                          (float4*)out, (float4*)lacc);
    denom_kernel<<<512, 1024, 0, stream>>>(qb, kb, lacc);
    attend_kernel<<<512, 1024, 0, stream>>>(qb, kb, vt2, lacc, Wpost, out);
}

// Round 7
// 235.146 us; speedup vs baseline: 2.0380x; 1.1457x over previous
//
#include <hip/hip_runtime.h>
#include <math.h>

typedef _Float16 Hh;
typedef __attribute__((ext_vector_type(8))) _Float16 half8;
typedef __attribute__((ext_vector_type(4))) _Float16 half4;
typedef __attribute__((ext_vector_type(4))) float float4v;

#define B_ 2
#define H_ 16
#define N_ 2048
#define D_ 64
#define ND_ (N_*D_)
#define C1 0.04508422f   // (1/32)*log2(e); softmax in base-2 throughout

// Barrier WITHOUT the vmcnt(0) drain __syncthreads would emit.
#define BAR() asm volatile("s_waitcnt lgkmcnt(0)\n\ts_barrier" ::: "memory")

// attend LDS layouts (i-tile 32), conflict-free strides:
// Ebuf: [j(32)][i(32)][f(16+4pad)]  j-stride 644 halves, i-stride 20
#define EB_JS 644
#define EB_IS 20
// Pm: [e(16)][i(32)][j(32+4pad)]    e-stride 1156 halves, i-stride 36
// (1156 h = 2312 B; 2560 B (R3) was ≡ 0 mod 128 B -> 16-way conflicts)
#define PM_ES 1156
#define PM_IS 36

// ---------------------------------------------------------------------------
// K1: prep. (R6 version, no launch_bounds)
// ---------------------------------------------------------------------------
__global__ void prep_kernel(const float* __restrict__ q,
    const float* __restrict__ k, const float* __restrict__ v,
    const float* __restrict__ Wpre,
    Hh* __restrict__ qb, Hh* __restrict__ kb, Hh* __restrict__ vt2,
    float4* __restrict__ out4, float4* __restrict__ lacc4)
{
    int tid = threadIdx.x;
    int bid = blockIdx.x;
    if (bid < 512) {
        __shared__ float wsh[256];
        wsh[tid] = Wpre[tid];
        __syncthreads();
        int tensor = bid >> 8;
        int g = ((bid & 255) << 8) | tid;     // 0 .. 65535
        int b = g >> 15;
        int r = g & 32767;                    // (n,d4): n*16 + d4
        const float4* src = (const float4*)(tensor ? k : q);
        Hh* dst = tensor ? kb : qb;
        float4 x[16];
        #pragma unroll
        for (int f=0; f<16; f++) x[f] = src[(size_t)(b*16+f)*32768 + r];
        #pragma unroll
        for (int e=0; e<16; e++) {
            float4 a = make_float4(0.f,0.f,0.f,0.f);
            #pragma unroll
            for (int f=0; f<16; f++) {
                float wv = wsh[e*16+f];
                a.x += wv*x[f].x; a.y += wv*x[f].y; a.z += wv*x[f].z; a.w += wv*x[f].w;
            }
            half4 hv; hv[0]=(Hh)a.x; hv[1]=(Hh)a.y; hv[2]=(Hh)a.z; hv[3]=(Hh)a.w;
            *(half4*)(dst + (size_t)(b*16+e)*ND_ + (size_t)r*4) = hv;
        }
    } else if (bid < 768) {
        __shared__ Hh tile[64*48];            // [d][j], stride 48 halves
        int tb = bid - 512;                   // 0..255
        int be = tb >> 3;                     // 0..31
        int jtg = tb & 7;
        const float4* v4 = (const float4*)v;
        for (int u=0; u<8; u++) {
            int jt = jtg*8 + u;               // 0..63
            #pragma unroll
            for (int p=0; p<2; p++) {
                int j = p*16 + (tid>>4);
                int d4 = tid & 15;
                float4 val = v4[(size_t)be*32768 + (size_t)(jt*32+j)*16 + d4];
                tile[(d4*4+0)*48 + j] = (Hh)val.x;
                tile[(d4*4+1)*48 + j] = (Hh)val.y;
                tile[(d4*4+2)*48 + j] = (Hh)val.z;
                tile[(d4*4+3)*48 + j] = (Hh)val.w;
            }
            BAR();
            {
                int d = tid >> 2;
                int jc = (tid & 3) * 8;
                half8 o;
                #pragma unroll
                for (int z=0; z<8; z++) o[z] = tile[d*48 + jc + z];
                *(half8*)(vt2 + ((size_t)(be*64) + jt)*2048 + (size_t)tid*8) = o;
            }
            BAR();
        }
    } else {
        // zero out + lacc. out = 2*16*2048*64 floats = 1048576 float4.
        int zid = (bid - 768) * 256 + tid;    // 0 .. 262143
        float4 zz = make_float4(0.f,0.f,0.f,0.f);
        #pragma unroll
        for (int u=0; u<4; u++) out4[(size_t)u*262144 + zid] = zz;
        if (zid < 16384) lacc4[zid] = zz;
    }
}

// ---------------------------------------------------------------------------
// K2: denominators — REVERT to the R1/R2 version (i-tile 64, 256 balanced
// blocks). The R3+ i-tile-32 rewrite doubled K re-read traffic (135->270 MB)
// and coincides with rest 125 -> 140 µs. This is the version measured inside
// the rest=125 era.
// ---------------------------------------------------------------------------
__global__ __launch_bounds__(1024,4) void denom_kernel(const Hh* __restrict__ qb,
    const Hh* __restrict__ kb, float* __restrict__ lacc_g)
{
    int bid = blockIdx.x;                 // 0..255
    int s = bid & 7;                      // j-slab, XCD-aligned
    int idx = bid >> 3;                   // 0..31
    int b = idx & 1;
    int pr = idx >> 1;                    // 0..15: triangle pair id
    int tid = threadIdx.x;
    int lane = tid & 63, w = tid >> 6;    // w = head f, 0..15
    int qd = lane >> 4, c = lane & 15;

    const Hh* qh = qb + (size_t)(b*16 + w)*ND_;
    const Hh* kh = kb + (size_t)(b*16 + w)*ND_;

    for (int hf = 0; hf < 2; hf++) {
        int it = hf ? (31 - pr) : pr;     // 64-row i-tile index
        int i0 = it * 64;

        half8 aq[4][2];
        #pragma unroll
        for (int ig=0; ig<4; ig++) {
            const Hh* qr = qh + (size_t)(i0 + ig*16 + c)*64 + qd*8;
            aq[ig][0] = *(const half8*)qr;
            aq[ig][1] = *(const half8*)(qr+32);
        }
        float lacc[4][4];
        #pragma unroll
        for (int ig=0; ig<4; ig++)
            #pragma unroll
            for (int r=0; r<4; r++) lacc[ig][r] = 0.f;

        int jtmax = 2*it + 1;             // last 32-j tile touching row i0+63
        for (int jt = s; jt <= jtmax; jt += 8) {
            int j0 = jt*32;
            #pragma unroll
            for (int jh=0; jh<2; jh++) {
                const Hh* kr = kh + (size_t)(j0 + jh*16 + c)*64 + qd*8;
                half8 b0 = *(const half8*)kr;
                half8 b1 = *(const half8*)(kr+32);
                int j = j0 + jh*16 + c;
                #pragma unroll
                for (int ig=0; ig<4; ig++) {
                    float4v sv = {0.f,0.f,0.f,0.f};
                    sv = __builtin_amdgcn_mfma_f32_16x16x32_f16(aq[ig][0], b0, sv, 0,0,0);
                    sv = __builtin_amdgcn_mfma_f32_16x16x32_f16(aq[ig][1], b1, sv, 0,0,0);
                    #pragma unroll
                    for (int r=0; r<4; r++) {
                        int i = i0 + ig*16 + qd*4 + r;
                        float ev = (j <= i) ? __builtin_amdgcn_exp2f(sv[r]*C1) : 0.f;
                        lacc[ig][r] += ev;
                    }
                }
            }
        }
        #pragma unroll
        for (int ig=0; ig<4; ig++) {
            #pragma unroll
            for (int r=0; r<4; r++) {
                float vs = lacc[ig][r];
                vs += __shfl_xor(vs, 1);
                vs += __shfl_xor(vs, 2);
                vs += __shfl_xor(vs, 4);
                vs += __shfl_xor(vs, 8);
                if (c == 0)
                    unsafeAtomicAdd(&lacc_g[(size_t)(b*16+w)*N_ + i0 + ig*16 + qd*4 + r], vs);
            }
        }
    }
}

// ---------------------------------------------------------------------------
// K3: main fused pass — R3's best-measured config (256 blocks, 4 slabs,
// 1 head/wave, 16 waves, i-tile 32) with two proven/targeted additions:
//  (1) Pm stride 1156 (R6-verified; kills the 16-way Pm conflict that cost
//      R3 18.9M conflict-cycles).
//  (2) Register prefetch: K(jt+4) and V(jt+4) issued at the TOP of each
//      iteration; mix + barrier + PV cover their ~600-cy L2/L3 latency.
//      In R3 both load chains issued after the mid-barrier and were consumed
//      immediately — two serial latency chains per iteration.
// Register budget: R3 body 64 + kk16 + vv16 + kn/vn transient 32 ~= 112
// < 128 cap of (1024,4). No spills expected (R4's spill was 4-heads/wave).
// ---------------------------------------------------------------------------
__global__ __launch_bounds__(1024,4) void attend_kernel(const Hh* __restrict__ qb,
    const Hh* __restrict__ kb, const Hh* __restrict__ vt2,
    const float* __restrict__ lacc_g, const float* __restrict__ Wpost,
    float* __restrict__ out)
{
    __shared__ Hh Ebuf[32*EB_JS];   // 41216 B
    __shared__ Hh Pm[16*PM_ES];     // 36992 B

    int bid = blockIdx.x;                      // 0..255
    int s = (bid & 7) >> 1;                    // slab 0..3, XCD-pair aligned
    int b = bid & 1;
    int pr = bid >> 3;                         // 0..31: triangle pair id

    int tid = threadIdx.x;
    int lane = tid & 63, w = tid >> 6;         // w 0..15
    int qd = lane >> 4, c = lane & 15;

    // ---- mix role constants
    int jh2 = w & 1, ib = 4*(w >> 1);
    half4 wf;   // B[k=f=qd*4+z][n=e=c] = Wpost[e][f]
    #pragma unroll
    for (int z=0; z<4; z++) wf[z] = (Hh)Wpost[c*16 + qd*4 + z];

    for (int hf = 0; hf < 2; hf++) {
        int it = hf ? (63 - pr) : pr;          // 32-row i-tile index
        if (s > it) continue;                  // uniform per block
        int i0 = it * 32;

        // ---- scores state: head f = w, both ig
        half8 aq[2][2];
        float lgr[2][4];
        #pragma unroll
        for (int ig=0; ig<2; ig++) {
            const Hh* qr = qb + (size_t)((b*16+w)*N_ + i0 + ig*16 + c)*64 + qd*8;
            aq[ig][0] = *(const half8*)qr;
            aq[ig][1] = *(const half8*)(qr+32);
            #pragma unroll
            for (int r=0; r<4; r++)
                lgr[ig][r] = __builtin_amdgcn_logf(
                    lacc_g[(size_t)(b*16+w)*N_ + i0 + ig*16 + qd*4 + r]);
        }

        float4v acc[2][4];
        #pragma unroll
        for (int ig=0; ig<2; ig++) for (int nc=0; nc<4; nc++)
            acc[ig][nc] = (float4v){0.f,0.f,0.f,0.f};

        auto loadK = [&](int jt, half8 (&kk)[2][2]) {
            #pragma unroll
            for (int jh=0; jh<2; jh++) {
                const Hh* kr = kb + (size_t)((b*16+w)*N_ + jt*32 + jh*16 + c)*64 + qd*8;
                kk[jh][0] = *(const half8*)kr;
                kk[jh][1] = *(const half8*)(kr+32);
            }
        };
        auto loadV = [&](int jt, half8 (&vv)[4]) {
            #pragma unroll
            for (int nc=0; nc<4; nc++)
                vv[nc] = *(const half8*)(vt2 +
                    (size_t)((b*16+w)*64 + jt)*2048 + (nc*16+c)*32 + qd*8);
        };

        auto scores = [&](int jt, half8 (&kk)[2][2]) {
            #pragma unroll
            for (int jh=0; jh<2; jh++) {
                int j = jt*32 + jh*16 + c;
                #pragma unroll
                for (int ig=0; ig<2; ig++) {
                    float4v sv = {0.f,0.f,0.f,0.f};
                    sv = __builtin_amdgcn_mfma_f32_16x16x32_f16(aq[ig][0], kk[jh][0], sv, 0,0,0);
                    sv = __builtin_amdgcn_mfma_f32_16x16x32_f16(aq[ig][1], kk[jh][1], sv, 0,0,0);
                    #pragma unroll
                    for (int r=0; r<4; r++) {
                        int i = i0 + ig*16 + qd*4 + r;
                        float ev = (j <= i) ?
                            __builtin_amdgcn_exp2f(sv[r]*C1 - lgr[ig][r]) : 0.f;
                        Ebuf[(size_t)(jh*16+c)*EB_JS + (ig*16+qd*4+r)*EB_IS + w] = (Hh)ev;
                    }
                }
            }
        };

        half8 kk[2][2], vv[4];
        loadK(s, kk);
        loadV(s, vv);
        scores(s, kk);
        BAR();

        for (int jt = s; jt <= it; jt += 4) {
            bool more = (jt + 4 <= it);
            // ---- prefetch next tile's K and V into registers ----
            half8 kn[2][2], vn[4];
            if (more) { loadK(jt + 4, kn); loadV(jt + 4, vn); }
            // ---- head mix: Pm[e,i,j] for this wave's (jh2, i-quad) ----
            #pragma unroll
            for (int ii=0; ii<4; ii++) {
                int i = ib + ii;
                half4 ef = *(const half4*)&Ebuf[(jh2*16+c)*EB_JS + i*EB_IS + qd*4];
                float4v cc = {0.f,0.f,0.f,0.f};
                cc = __builtin_amdgcn_mfma_f32_16x16x16f16(ef, wf, cc, 0,0,0);
                half4 hv;
                #pragma unroll
                for (int r=0; r<4; r++) hv[r] = (Hh)cc[r];
                *(half4*)&Pm[c*PM_ES + i*PM_IS + jh2*16 + qd*4] = hv;
            }
            BAR();
            // ---- PV(jt): head e=w, both ig (V already in regs) ----
            #pragma unroll
            for (int nc=0; nc<4; nc++) {
                #pragma unroll
                for (int ig=0; ig<2; ig++) {
                    half8 pa = *(const half8*)&Pm[w*PM_ES + (ig*16+c)*PM_IS + qd*8];
                    acc[ig][nc] = __builtin_amdgcn_mfma_f32_16x16x32_f16(pa, vv[nc], acc[ig][nc], 0,0,0);
                }
            }
            // ---- scores(jt+4) with prefetched K ----
            if (more) {
                scores(jt + 4, kn);
                #pragma unroll
                for (int nc=0; nc<4; nc++) vv[nc] = vn[nc];
            }
            BAR();
        }

        // ---- accumulate partial O (nc order rotated by slab) ----
        #pragma unroll
        for (int ig=0; ig<2; ig++) {
            #pragma unroll
            for (int nc0=0; nc0<4; nc0++) {
                int nc = (nc0 + s) & 3;
                #pragma unroll
                for (int r=0; r<4; r++)
                    unsafeAtomicAdd(&out[(size_t)((b*16+w)*N_ + i0 + ig*16 + qd*4 + r)*64 + nc*16 + c],
                                    acc[ig][nc][r]);
            }
        }
    }
}

extern "C" void kernel_launch(void* const* d_in, const int* in_sizes, int n_in,
                              void* d_out, int out_size, void* d_ws, size_t ws_size,
                              hipStream_t stream) {
    const float* q     = (const float*)d_in[0];
    const float* k     = (const float*)d_in[1];
    const float* v     = (const float*)d_in[2];
    const float* Wpre  = (const float*)d_in[3];
    const float* Wpost = (const float*)d_in[4];
    float* out = (float*)d_out;

    size_t tsz = (size_t)B_*H_*N_*D_;       // 4 Mi halves = 8 MB each
    Hh* qb = (Hh*)d_ws;
    Hh* kb = qb + tsz;
    Hh* vt2 = kb + tsz;
    float* lacc = (float*)(vt2 + tsz);      // 24 MB offset, 256 KB

    prep_kernel<<<1792, 256, 0, stream>>>(q, k, v, Wpre, qb, kb, vt2,
                                          (float4*)out, (float4*)lacc);
    denom_kernel<<<256, 1024, 0, stream>>>(qb, kb, lacc);
    attend_kernel<<<256, 1024, 0, stream>>>(qb, kb, vt2, lacc, Wpost, out);
}

// Round 8
// 229.340 us; speedup vs baseline: 2.0896x; 1.0253x over previous
//
#include <hip/hip_runtime.h>
#include <math.h>

typedef _Float16 Hh;
typedef __attribute__((ext_vector_type(8))) _Float16 half8;
typedef __attribute__((ext_vector_type(4))) _Float16 half4;
typedef __attribute__((ext_vector_type(4))) float float4v;

#define B_ 2
#define H_ 16
#define N_ 2048
#define D_ 64
#define ND_ (N_*D_)
#define C1 0.04508422f   // (1/32)*log2(e); softmax in base-2 throughout

// Barrier WITHOUT the vmcnt(0) drain __syncthreads would emit.
#define BAR() asm volatile("s_waitcnt lgkmcnt(0)\n\ts_barrier" ::: "memory")

// attend LDS layouts (i-tile 32), conflict-free strides:
// Ebuf: [j(32)][i(32)][f(16+4pad)]  j-stride 644 halves, i-stride 20
#define EB_JS 644
#define EB_IS 20
// Pm: [e(16)][i(32)][j(32+4pad)]    e-stride 1156 halves, i-stride 36
#define PM_ES 1156
#define PM_IS 36

// ---------------------------------------------------------------------------
// K1: prep. (unchanged R6/R7 version, no launch_bounds)
// ---------------------------------------------------------------------------
__global__ void prep_kernel(const float* __restrict__ q,
    const float* __restrict__ k, const float* __restrict__ v,
    const float* __restrict__ Wpre,
    Hh* __restrict__ qb, Hh* __restrict__ kb, Hh* __restrict__ vt2,
    float4* __restrict__ out4, float4* __restrict__ lacc4)
{
    int tid = threadIdx.x;
    int bid = blockIdx.x;
    if (bid < 512) {
        __shared__ float wsh[256];
        wsh[tid] = Wpre[tid];
        __syncthreads();
        int tensor = bid >> 8;
        int g = ((bid & 255) << 8) | tid;     // 0 .. 65535
        int b = g >> 15;
        int r = g & 32767;                    // (n,d4): n*16 + d4
        const float4* src = (const float4*)(tensor ? k : q);
        Hh* dst = tensor ? kb : qb;
        float4 x[16];
        #pragma unroll
        for (int f=0; f<16; f++) x[f] = src[(size_t)(b*16+f)*32768 + r];
        #pragma unroll
        for (int e=0; e<16; e++) {
            float4 a = make_float4(0.f,0.f,0.f,0.f);
            #pragma unroll
            for (int f=0; f<16; f++) {
                float wv = wsh[e*16+f];
                a.x += wv*x[f].x; a.y += wv*x[f].y; a.z += wv*x[f].z; a.w += wv*x[f].w;
            }
            half4 hv; hv[0]=(Hh)a.x; hv[1]=(Hh)a.y; hv[2]=(Hh)a.z; hv[3]=(Hh)a.w;
            *(half4*)(dst + (size_t)(b*16+e)*ND_ + (size_t)r*4) = hv;
        }
    } else if (bid < 768) {
        __shared__ Hh tile[64*48];            // [d][j], stride 48 halves
        int tb = bid - 512;                   // 0..255
        int be = tb >> 3;                     // 0..31
        int jtg = tb & 7;
        const float4* v4 = (const float4*)v;
        for (int u=0; u<8; u++) {
            int jt = jtg*8 + u;               // 0..63
            #pragma unroll
            for (int p=0; p<2; p++) {
                int j = p*16 + (tid>>4);
                int d4 = tid & 15;
                float4 val = v4[(size_t)be*32768 + (size_t)(jt*32+j)*16 + d4];
                tile[(d4*4+0)*48 + j] = (Hh)val.x;
                tile[(d4*4+1)*48 + j] = (Hh)val.y;
                tile[(d4*4+2)*48 + j] = (Hh)val.z;
                tile[(d4*4+3)*48 + j] = (Hh)val.w;
            }
            BAR();
            {
                int d = tid >> 2;
                int jc = (tid & 3) * 8;
                half8 o;
                #pragma unroll
                for (int z=0; z<8; z++) o[z] = tile[d*48 + jc + z];
                *(half8*)(vt2 + ((size_t)(be*64) + jt)*2048 + (size_t)tid*8) = o;
            }
            BAR();
        }
    } else {
        // zero out + lacc. out = 2*16*2048*64 floats = 1048576 float4.
        int zid = (bid - 768) * 256 + tid;    // 0 .. 262143
        float4 zz = make_float4(0.f,0.f,0.f,0.f);
        #pragma unroll
        for (int u=0; u<4; u++) out4[(size_t)u*262144 + zid] = zz;
        if (zid < 16384) lacc4[zid] = zz;
    }
}

// ---------------------------------------------------------------------------
// K2: denominators — R7 body, plus amdgpu_waves_per_eu(4,4): pins the
// compiler to the 1-block/CU occupancy it actually gets, raising the VGPR
// budget 64 -> 128 so the ~75-reg live set (aq 32 + lacc 16 + K frags 16 +
// addressing) stops spilling in the hot loop.
// ---------------------------------------------------------------------------
__global__ __launch_bounds__(1024)
__attribute__((amdgpu_waves_per_eu(4,4)))
void denom_kernel(const Hh* __restrict__ qb,
    const Hh* __restrict__ kb, float* __restrict__ lacc_g)
{
    int bid = blockIdx.x;                 // 0..255
    int s = bid & 7;                      // j-slab, XCD-aligned
    int idx = bid >> 3;                   // 0..31
    int b = idx & 1;
    int pr = idx >> 1;                    // 0..15: triangle pair id
    int tid = threadIdx.x;
    int lane = tid & 63, w = tid >> 6;    // w = head f, 0..15
    int qd = lane >> 4, c = lane & 15;

    const Hh* qh = qb + (size_t)(b*16 + w)*ND_;
    const Hh* kh = kb + (size_t)(b*16 + w)*ND_;

    for (int hf = 0; hf < 2; hf++) {
        int it = hf ? (31 - pr) : pr;     // 64-row i-tile index
        int i0 = it * 64;

        half8 aq[4][2];
        #pragma unroll
        for (int ig=0; ig<4; ig++) {
            const Hh* qr = qh + (size_t)(i0 + ig*16 + c)*64 + qd*8;
            aq[ig][0] = *(const half8*)qr;
            aq[ig][1] = *(const half8*)(qr+32);
        }
        float lacc[4][4];
        #pragma unroll
        for (int ig=0; ig<4; ig++)
            #pragma unroll
            for (int r=0; r<4; r++) lacc[ig][r] = 0.f;

        int jtmax = 2*it + 1;             // last 32-j tile touching row i0+63
        for (int jt = s; jt <= jtmax; jt += 8) {
            int j0 = jt*32;
            #pragma unroll
            for (int jh=0; jh<2; jh++) {
                const Hh* kr = kh + (size_t)(j0 + jh*16 + c)*64 + qd*8;
                half8 b0 = *(const half8*)kr;
                half8 b1 = *(const half8*)(kr+32);
                int j = j0 + jh*16 + c;
                #pragma unroll
                for (int ig=0; ig<4; ig++) {
                    float4v sv = {0.f,0.f,0.f,0.f};
                    sv = __builtin_amdgcn_mfma_f32_16x16x32_f16(aq[ig][0], b0, sv, 0,0,0);
                    sv = __builtin_amdgcn_mfma_f32_16x16x32_f16(aq[ig][1], b1, sv, 0,0,0);
                    #pragma unroll
                    for (int r=0; r<4; r++) {
                        int i = i0 + ig*16 + qd*4 + r;
                        float ev = (j <= i) ? __builtin_amdgcn_exp2f(sv[r]*C1) : 0.f;
                        lacc[ig][r] += ev;
                    }
                }
            }
        }
        #pragma unroll
        for (int ig=0; ig<4; ig++) {
            #pragma unroll
            for (int r=0; r<4; r++) {
                float vs = lacc[ig][r];
                vs += __shfl_xor(vs, 1);
                vs += __shfl_xor(vs, 2);
                vs += __shfl_xor(vs, 4);
                vs += __shfl_xor(vs, 8);
                if (c == 0)
                    unsafeAtomicAdd(&lacc_g[(size_t)(b*16+w)*N_ + i0 + ig*16 + qd*4 + r], vs);
            }
        }
    }
}

// ---------------------------------------------------------------------------
// K3: main fused pass — R7 body VERBATIM, plus amdgpu_waves_per_eu(4,4).
// R7's counters showed the prefetch spilled (VGPR stuck at 64 while FETCH
// +20 MB / WRITE +37 MB of scratch traffic): the compiler chose 64 VGPR to
// enable 2 blocks/CU, but 78.3 KB LDS means the second block never becomes
// resident (R6 measured occupancy ~38% with 512 blocks). Pinning waves/EU
// to exactly 4 removes the incentive: budget 128 VGPR, live set ~115, no
// spills, kn/vn genuinely in flight across mix+BAR+PV.
// ---------------------------------------------------------------------------
__global__ __launch_bounds__(1024)
__attribute__((amdgpu_waves_per_eu(4,4)))
void attend_kernel(const Hh* __restrict__ qb,
    const Hh* __restrict__ kb, const Hh* __restrict__ vt2,
    const float* __restrict__ lacc_g, const float* __restrict__ Wpost,
    float* __restrict__ out)
{
    __shared__ Hh Ebuf[32*EB_JS];   // 41216 B
    __shared__ Hh Pm[16*PM_ES];     // 36992 B

    int bid = blockIdx.x;                      // 0..255
    int s = (bid & 7) >> 1;                    // slab 0..3, XCD-pair aligned
    int b = bid & 1;
    int pr = bid >> 3;                         // 0..31: triangle pair id

    int tid = threadIdx.x;
    int lane = tid & 63, w = tid >> 6;         // w 0..15
    int qd = lane >> 4, c = lane & 15;

    // ---- mix role constants
    int jh2 = w & 1, ib = 4*(w >> 1);
    half4 wf;   // B[k=f=qd*4+z][n=e=c] = Wpost[e][f]
    #pragma unroll
    for (int z=0; z<4; z++) wf[z] = (Hh)Wpost[c*16 + qd*4 + z];

    for (int hf = 0; hf < 2; hf++) {
        int it = hf ? (63 - pr) : pr;          // 32-row i-tile index
        if (s > it) continue;                  // uniform per block
        int i0 = it * 32;

        // ---- scores state: head f = w, both ig
        half8 aq[2][2];
        float lgr[2][4];
        #pragma unroll
        for (int ig=0; ig<2; ig++) {
            const Hh* qr = qb + (size_t)((b*16+w)*N_ + i0 + ig*16 + c)*64 + qd*8;
            aq[ig][0] = *(const half8*)qr;
            aq[ig][1] = *(const half8*)(qr+32);
            #pragma unroll
            for (int r=0; r<4; r++)
                lgr[ig][r] = __builtin_amdgcn_logf(
                    lacc_g[(size_t)(b*16+w)*N_ + i0 + ig*16 + qd*4 + r]);
        }

        float4v acc[2][4];
        #pragma unroll
        for (int ig=0; ig<2; ig++) for (int nc=0; nc<4; nc++)
            acc[ig][nc] = (float4v){0.f,0.f,0.f,0.f};

        auto loadK = [&](int jt, half8 (&kk)[2][2]) {
            #pragma unroll
            for (int jh=0; jh<2; jh++) {
                const Hh* kr = kb + (size_t)((b*16+w)*N_ + jt*32 + jh*16 + c)*64 + qd*8;
                kk[jh][0] = *(const half8*)kr;
                kk[jh][1] = *(const half8*)(kr+32);
            }
        };
        auto loadV = [&](int jt, half8 (&vv)[4]) {
            #pragma unroll
            for (int nc=0; nc<4; nc++)
                vv[nc] = *(const half8*)(vt2 +
                    (size_t)((b*16+w)*64 + jt)*2048 + (nc*16+c)*32 + qd*8);
        };

        auto scores = [&](int jt, half8 (&kk)[2][2]) {
            #pragma unroll
            for (int jh=0; jh<2; jh++) {
                int j = jt*32 + jh*16 + c;
                #pragma unroll
                for (int ig=0; ig<2; ig++) {
                    float4v sv = {0.f,0.f,0.f,0.f};
                    sv = __builtin_amdgcn_mfma_f32_16x16x32_f16(aq[ig][0], kk[jh][0], sv, 0,0,0);
                    sv = __builtin_amdgcn_mfma_f32_16x16x32_f16(aq[ig][1], kk[jh][1], sv, 0,0,0);
                    #pragma unroll
                    for (int r=0; r<4; r++) {
                        int i = i0 + ig*16 + qd*4 + r;
                        float ev = (j <= i) ?
                            __builtin_amdgcn_exp2f(sv[r]*C1 - lgr[ig][r]) : 0.f;
                        Ebuf[(size_t)(jh*16+c)*EB_JS + (ig*16+qd*4+r)*EB_IS + w] = (Hh)ev;
                    }
                }
            }
        };

        half8 kk[2][2], vv[4];
        loadK(s, kk);
        loadV(s, vv);
        scores(s, kk);
        BAR();

        for (int jt = s; jt <= it; jt += 4) {
            bool more = (jt + 4 <= it);
            // ---- prefetch next tile's K and V into registers ----
            half8 kn[2][2], vn[4];
            if (more) { loadK(jt + 4, kn); loadV(jt + 4, vn); }
            // ---- head mix: Pm[e,i,j] for this wave's (jh2, i-quad) ----
            #pragma unroll
            for (int ii=0; ii<4; ii++) {
                int i = ib + ii;
                half4 ef = *(const half4*)&Ebuf[(jh2*16+c)*EB_JS + i*EB_IS + qd*4];
                float4v cc = {0.f,0.f,0.f,0.f};
                cc = __builtin_amdgcn_mfma_f32_16x16x16f16(ef, wf, cc, 0,0,0);
                half4 hv;
                #pragma unroll
                for (int r=0; r<4; r++) hv[r] = (Hh)cc[r];
                *(half4*)&Pm[c*PM_ES + i*PM_IS + jh2*16 + qd*4] = hv;
            }
            BAR();
            // ---- PV(jt): head e=w, both ig (V already in regs) ----
            #pragma unroll
            for (int nc=0; nc<4; nc++) {
                #pragma unroll
                for (int ig=0; ig<2; ig++) {
                    half8 pa = *(const half8*)&Pm[w*PM_ES + (ig*16+c)*PM_IS + qd*8];
                    acc[ig][nc] = __builtin_amdgcn_mfma_f32_16x16x32_f16(pa, vv[nc], acc[ig][nc], 0,0,0);
                }
            }
            // ---- scores(jt+4) with prefetched K ----
            if (more) {
                scores(jt + 4, kn);
                #pragma unroll
                for (int nc=0; nc<4; nc++) vv[nc] = vn[nc];
            }
            BAR();
        }

        // ---- accumulate partial O (nc order rotated by slab) ----
        #pragma unroll
        for (int ig=0; ig<2; ig++) {
            #pragma unroll
            for (int nc0=0; nc0<4; nc0++) {
                int nc = (nc0 + s) & 3;
                #pragma unroll
                for (int r=0; r<4; r++)
                    unsafeAtomicAdd(&out[(size_t)((b*16+w)*N_ + i0 + ig*16 + qd*4 + r)*64 + nc*16 + c],
                                    acc[ig][nc][r]);
            }
        }
    }
}

extern "C" void kernel_launch(void* const* d_in, const int* in_sizes, int n_in,
                              void* d_out, int out_size, void* d_ws, size_t ws_size,
                              hipStream_t stream) {
    const float* q     = (const float*)d_in[0];
    const float* k     = (const float*)d_in[1];
    const float* v     = (const float*)d_in[2];
    const float* Wpre  = (const float*)d_in[3];
    const float* Wpost = (const float*)d_in[4];
    float* out = (float*)d_out;

    size_t tsz = (size_t)B_*H_*N_*D_;       // 4 Mi halves = 8 MB each
    Hh* qb = (Hh*)d_ws;
    Hh* kb = qb + tsz;
    Hh* vt2 = kb + tsz;
    float* lacc = (float*)(vt2 + tsz);      // 24 MB offset, 256 KB

    prep_kernel<<<1792, 256, 0, stream>>>(q, k, v, Wpre, qb, kb, vt2,
                                          (float4*)out, (float4*)lacc);
    denom_kernel<<<256, 1024, 0, stream>>>(qb, kb, lacc);
    attend_kernel<<<256, 1024, 0, stream>>>(qb, kb, vt2, lacc, Wpost, out);
}